// Round 3
// 319.102 us; speedup vs baseline: 1.0112x; 1.0112x over previous
//
#include <hip/hip_runtime.h>

// Problem constants (reference: T=256, L=32, C=8, B=16, D=512)
#define TT 256
#define LL 32
#define CC 8
#define BB 16
#define DD 512
#define D4 (DD / 4)          // 128 float4 per d-row

// Output layout (floats): fc | fm | fb
#define FC_ELEMS ((long)BB * LL * LL * CC * DD)   // 67,108,864
#define FM_ELEMS ((long)BB * LL * LL * DD)        //  8,388,608
#define FM_OFF   FC_ELEMS
#define FB_OFF   (FC_ELEMS + FM_ELEMS)            // 75,497,472

// Workspace layout (floats): S [B][257][D] exclusive prefix table
#define S_ROWS   (TT + 1)                         // 257

// Merged scan kernel decomposition: 32 chunks of 8 t-rows, 8 d4-lanes/block
#define SCHUNK   8
#define NSCHUNK  (TT / SCHUNK)                    // 32
#define D4PB     8                                // d4 per block

__device__ __forceinline__ float4 f4add(float4 a, float4 b) {
  return make_float4(a.x + b.x, a.y + b.y, a.z + b.z, a.w + b.w);
}
__device__ __forceinline__ float4 f4sub(float4 a, float4 b) {
  return make_float4(a.x - b.x, a.y - b.y, a.z - b.z, a.w - b.w);
}

// Non-temporal (evict-first, no L2 allocate) store: protects the S working
// set in L2 from being thrashed by the 302 MB fc/fm/fb write stream.
// __builtin_nontemporal_store needs a NATIVE vector type, not HIP's float4
// class — round-trip through ext_vector_type(4).
typedef float nf4 __attribute__((ext_vector_type(4)));
__device__ __forceinline__ void ntstore(float4* p, float4 v) {
  nf4 nv;
  nv.x = v.x; nv.y = v.y; nv.z = v.z; nv.w = v.w;
  __builtin_nontemporal_store(nv, (nf4*)p);
}

// ---------------------------------------------------------------------------
// Kernel 1 (merged chunk_sum + scan): exclusive prefix table
// S[b][p][d] = sum_{t<p} f[b][t][d]  (p in [0,256]),  plus fb = f^T.
// Block = 256 threads = 32 chunks x 8 d4; grid = B x (D4/8) = 256 blocks
// (1 block/CU -> all CUs active). Cross-chunk offsets via one LDS round.
__global__ __launch_bounds__(256) void scan_fb_kernel(
    const float4* __restrict__ f4, float4* __restrict__ S4,
    float4* __restrict__ fb4) {
  __shared__ float4 part[NSCHUNK][D4PB];   // 4 KB

  int b = blockIdx.x >> 4;              // 0..15
  int d4blk = blockIdx.x & 15;          // 0..15
  int d4local = threadIdx.x & (D4PB - 1);
  int chunk = threadIdx.x >> 3;         // 0..31
  int d4 = d4blk * D4PB + d4local;      // 0..127

  // Load this thread's 8 t-rows once; keep in registers (32 VGPRs).
  const float4* fp = f4 + ((long)(b * TT + chunk * SCHUNK)) * D4 + d4;
  float4 vals[SCHUNK];
  float4 s = make_float4(0.f, 0.f, 0.f, 0.f);
#pragma unroll
  for (int i = 0; i < SCHUNK; ++i) {
    vals[i] = fp[(long)i * D4];
    s = f4add(s, vals[i]);
  }
  part[chunk][d4local] = s;
  __syncthreads();

  // Exclusive prefix over earlier chunks (same d4 column).
  float4 acc = make_float4(0.f, 0.f, 0.f, 0.f);
  for (int j = 0; j < chunk; ++j) acc = f4add(acc, part[j][d4local]);

  // Write S rows chunk*8+1 .. chunk*8+8 (regular stores: read next kernel,
  // we WANT these resident in L2).
  float4* Sp = S4 + ((long)b * S_ROWS + chunk * SCHUNK) * D4 + d4;
  if (chunk == 0) Sp[0] = make_float4(0.f, 0.f, 0.f, 0.f);
#pragma unroll
  for (int i = 0; i < SCHUNK; ++i) {
    acc = f4add(acc, vals[i]);
    Sp[(long)(i + 1) * D4] = acc;
  }

  // fb[b][d][t]: register transpose; this thread owns d = 4*d4..+3,
  // t = chunk*8..+7. Streamed output -> non-temporal.
  const float* v = (const float*)vals;  // v[4*i + dd] = f[t0+i][4*d4+dd]
#pragma unroll
  for (int dd = 0; dd < 4; ++dd) {
    float4* fbp = fb4 + (long)(b * DD + 4 * d4 + dd) * (TT / 4) + chunk * 2;
#pragma unroll
    for (int j = 0; j < 2; ++j) {
      float4 t = make_float4(v[(4 * j + 0) * 4 + dd], v[(4 * j + 1) * 4 + dd],
                             v[(4 * j + 2) * 4 + dd], v[(4 * j + 3) * 4 + dd]);
      ntstore(&fbp[j], t);
    }
  }
}

// ---------------------------------------------------------------------------
// Kernel 2: fc + fm from prefix differences, XCD-locality swizzle.
// 16384 blocks; assuming round-robin block->XCD dispatch, block i runs on
// XCD i&7. Remap so XCD k handles only b in {2k, 2k+1}: S working set per
// XCD = 2 * 514 KB ~= 1 MB < 4 MiB L2. All fc/fm stores are non-temporal
// so the 302 MB write stream does NOT evict the S lines.
// fc[b,l,m,c,:] = S[8l+(c+1)w] - S[8l+c*w], w = m-l+1; fm = S[8l+8w]-S[8l].
// l > m: write zeros (d_out is poisoned 0xAA before every timed launch).
__global__ __launch_bounds__(128) void fc_fm_kernel(
    const float* __restrict__ S, float* __restrict__ out) {
  int i = blockIdx.x;
  int vblk = ((i & 7) << 11) | (i >> 3);  // XCD-contiguous index
  int b = vblk >> 10;
  int l = (vblk >> 5) & (LL - 1);
  int m = vblk & (LL - 1);
  int d4 = threadIdx.x;  // 0..127

  float4* outv = (float4*)out;
  long blm = (long)((b * LL + l) * LL + m);
  long fc_base = blm * CC * D4;               // in float4 units
  long fm_base = FM_OFF / 4 + blm * D4;

  if (l > m) {
    float4 z = make_float4(0.f, 0.f, 0.f, 0.f);
#pragma unroll
    for (int c = 0; c < CC; ++c) ntstore(&outv[fc_base + (long)c * D4 + d4], z);
    ntstore(&outv[fm_base + d4], z);
    return;
  }

  int w = m - l + 1;
  const float4* S4 = (const float4*)S;
  long srow = (long)b * S_ROWS;

  float4 s[9];
#pragma unroll
  for (int c = 0; c <= 8; ++c) {
    int p = 8 * l + c * w;
    s[c] = S4[(srow + p) * D4 + d4];
  }

#pragma unroll
  for (int c = 0; c < CC; ++c)
    ntstore(&outv[fc_base + (long)c * D4 + d4], f4sub(s[c + 1], s[c]));
  ntstore(&outv[fm_base + d4], f4sub(s[8], s[0]));
}

// ---------------------------------------------------------------------------
extern "C" void kernel_launch(void* const* d_in, const int* in_sizes, int n_in,
                              void* d_out, int out_size, void* d_ws, size_t ws_size,
                              hipStream_t stream) {
  const float4* f4 = (const float4*)d_in[0];
  // d_in[1] is Wc — fully encoded in the closed-form index ranges.
  float* out = (float*)d_out;

  float4* S4 = (float4*)d_ws;                       // 8.4 MB prefix table
  float4* fb4 = (float4*)(out + FB_OFF);

  scan_fb_kernel<<<BB * (D4 / D4PB), 256, 0, stream>>>(f4, S4, fb4);
  fc_fm_kernel<<<BB * LL * LL, 128, 0, stream>>>((const float*)S4, out);
}